// Round 15
// baseline (90.827 us; speedup 1.0000x reference)
//
#include <hip/hip_runtime.h>
#include <hip/hip_bf16.h>
#include <stdint.h>

#define S_TOK 3072
#define E_DIM 1280
#define H_NUM 20
#define D_HEAD 64
#define NSEG 16

typedef __attribute__((ext_vector_type(8))) short short8;
typedef __attribute__((ext_vector_type(4))) float f32x4;

__device__ __forceinline__ unsigned short f2bf(float f){
  union { float f; unsigned int i; } u; u.f = f;
  unsigned int r = u.i + 0x7FFFu + ((u.i >> 16) & 1u);
  return (unsigned short)(r >> 16);
}

__device__ __forceinline__ void gload_lds16(const void* g, void* l){
  __builtin_amdgcn_global_load_lds((__attribute__((address_space(1))) void*)(g),
                                   (__attribute__((address_space(3))) void*)(l), 16, 0, 0);
}

// -------- f32 -> bf16 conversions for hs + Wq/Wk/Wv (Wo fused into attn) --------
__global__ void cvt_all(const float* __restrict__ hs,
                        const float* __restrict__ w0, const float* __restrict__ w1,
                        const float* __restrict__ w2,
                        unsigned short* __restrict__ hsb,
                        unsigned short* __restrict__ dqkv,
                        int nHS4, int nW4){
  int i = blockIdx.x * blockDim.x + threadIdx.x;
  const float* src;
  unsigned short* dst;
  size_t sj, dj;
  if (i < nHS4){
    src = hs; dst = hsb; sj = i; dj = i;
  } else {
    int t = i - nHS4;
    int w = t / nW4;
    if (w >= 3) return;
    int j = t - w * nW4;
    src = (w == 0) ? w0 : (w == 1) ? w1 : w2;
    sj = j;
    dst = dqkv; dj = (size_t)w * nW4 + j;
  }
  float4 v = reinterpret_cast<const float4*>(src)[sj];
  ushort4 o;
  o.x = f2bf(v.x); o.y = f2bf(v.y); o.z = f2bf(v.z); o.w = f2bf(v.w);
  reinterpret_cast<ushort4*>(dst)[dj] = o;
}

#define LGKM0 do { asm volatile("s_waitcnt lgkmcnt(0)" ::: "memory");         \
                   __builtin_amdgcn_sched_barrier(0); } while (0)
#define BAR   __builtin_amdgcn_s_barrier()

// ------------- QKV GEMM: 192x256 tile -> 240 blocks (94% chip fill) -------------
// (r14 winner, unchanged) 8 waves (2wm x 4wn), wave-tile 96x64, BK=64, dbuf,
// per-phase counted vmcnt with explicit ledger; stages target opposite dbuf.
__global__ __launch_bounds__(512, 2) void gemm_qkv(
    const unsigned short* __restrict__ A,
    const unsigned short* __restrict__ Bp,
    const float* __restrict__ bias0,   // bq
    const float* __restrict__ bias1,   // bv
    unsigned short* __restrict__ Oq,
    unsigned short* __restrict__ Ok,
    unsigned short* __restrict__ Ov,
    int K)
{
  constexpr int SLOT = (192 + 256) * 64;          // 28672 shorts per dbuf
  __shared__ __align__(16) unsigned short SH[2 * SLOT];

  const int nwg = gridDim.x;
  const int xcd = blockIdx.x & 7, ix = blockIdx.x >> 3;
  const int wg = xcd * (nwg >> 3) + ix;
  const int st = wg / 20, ii = wg % 20;           // st: 0..11
  const int bm = (st / 3) * 4 + ii / 5;           // 0..15
  const int bn = (st % 3) * 5 + ii % 5;           // 0..14
  const int row0 = bm * 192, col0 = bn * 256;

  const int tid  = threadIdx.x;
  const int lane = tid & 63;
  const int w    = tid >> 6;
  const int wm   = w >> 2;                        // 0..1
  const int wn   = w & 3;                         // 0..3

  const f32x4 fz = {0.f, 0.f, 0.f, 0.f};
  f32x4 acc[4][3][2];
#pragma unroll
  for (int qd = 0; qd < 4; ++qd)
#pragma unroll
    for (int m = 0; m < 3; ++m)
#pragma unroll
      for (int n = 0; n < 2; ++n) acc[qd][m][n] = fz;

  auto stA = [&](int t){                          // full A: 192x64, 3 loads
    unsigned short* d = SH + (t & 1) * SLOT;
    const unsigned short* g = A + (size_t)row0 * K + (t << 6);
#pragma unroll
    for (int i = 0; i < 3; ++i){
      int s = i * 512 + tid;
      int r = s >> 3, ks = (s & 7) ^ (r & 7);
      gload_lds16(g + (size_t)r * K + ks * 8, d + s * 8);
    }
  };
  auto stB = [&](int h, int t){                   // B half: 128x64, 2 loads
    unsigned short* d = SH + (t & 1) * SLOT + 12288 + h * 8192;
    const unsigned short* g = Bp + (size_t)(col0 + h * 128) * K + (t << 6);
#pragma unroll
    for (int i = 0; i < 2; ++i){
      int s = i * 512 + tid;
      int r = s >> 3, ks = (s & 7) ^ (r & 7);
      gload_lds16(g + (size_t)r * K + ks * 8, d + s * 8);
    }
  };

  short8 af[3][2], bf0[2][2], bf1[2][2];
  auto RA = [&](int mh, int db){
    const unsigned short* Ah = SH + db * SLOT;
#pragma unroll
    for (int m = 0; m < 3; ++m){
      int ra = mh * 96 + wm * 48 + m * 16 + (lane & 15);
#pragma unroll
      for (int kk = 0; kk < 2; ++kk){
        int sl = kk * 4 + (lane >> 4);
        af[m][kk] = *reinterpret_cast<const short8*>(&Ah[ra * 64 + ((sl ^ (ra & 7))) * 8]);
      }
    }
  };
  auto RB = [&](int nh, int db, short8 (*bf)[2]){
    const unsigned short* Bb = SH + db * SLOT + 12288;
#pragma unroll
    for (int n = 0; n < 2; ++n){
      int rb = nh * 128 + wn * 32 + n * 16 + (lane & 15);
#pragma unroll
      for (int kk = 0; kk < 2; ++kk){
        int sl = kk * 4 + (lane >> 4);
        bf[n][kk] = *reinterpret_cast<const short8*>(&Bb[rb * 64 + ((sl ^ (rb & 7))) * 8]);
      }
    }
  };

#define MF_Q(QD, BF)                                                          \
  do {                                                                        \
    __builtin_amdgcn_s_setprio(1);                                            \
    _Pragma("unroll")                                                         \
    for (int kk = 0; kk < 2; ++kk)                                            \
      _Pragma("unroll")                                                       \
      for (int m = 0; m < 3; ++m)                                             \
        _Pragma("unroll")                                                     \
        for (int n = 0; n < 2; ++n)                                           \
          acc[QD][m][n] = __builtin_amdgcn_mfma_f32_16x16x32_bf16(            \
              af[m][kk], BF[n][kk], acc[QD][m][n], 0, 0, 0);                  \
    __builtin_amdgcn_s_setprio(0);                                            \
  } while (0)

  const int nk = K >> 6;                          // 20
  stA(0); stB(0, 0); stB(1, 0);                   // 7 loads out
  for (int t = 0; t < nk; ++t){
    const int db = t & 1;
    const bool nx = (t + 1 < nk);
    // q0 (0,0): entry out=7 {A,B0,B1 of t}; force A+B0 -> leave 2
    asm volatile("s_waitcnt vmcnt(2)" ::: "memory");
    BAR;
    RA(0, db); RB(0, db, bf0);
    if (nx) stA(t + 1);                           // out: 2 -> 5
    LGKM0; MF_Q(0, bf0);
    // q1 (0,1): force B1(t) -> leave A(t+1)=3
    if (nx) asm volatile("s_waitcnt vmcnt(3)" ::: "memory");
    else    asm volatile("s_waitcnt vmcnt(0)" ::: "memory");
    BAR;
    RB(1, db, bf1);
    if (nx) stB(0, t + 1);                        // out: 3 -> 5
    LGKM0; MF_Q(1, bf1);
    // q2 (1,1): A(t) already forced at q0 - no wait
    BAR;
    RA(1, db);
    if (nx) stB(1, t + 1);                        // out: 5 -> 7
    LGKM0; MF_Q(2, bf1);
    // q3 (1,0): register-only
    BAR;
    MF_Q(3, bf0);
  }
  __syncthreads();

  // ---- coalesced scatter epilogue: two 96-row phases staged in LDS ----
  {
    unsigned short* Cs = SH;
    const int CSTR = 264;                         // 96 x 264 = 25344 <= SLOT
    const int mat = col0 / E_DIM;                 // 1280 % 256 == 0
    const int cc0 = col0 - mat * E_DIM;
    unsigned short* dst = (mat == 0) ? Oq : ((mat == 1) ? Ok : Ov);
    float bb[2][2];
#pragma unroll
    for (int nh = 0; nh < 2; ++nh)
#pragma unroll
      for (int n = 0; n < 2; ++n){
        int cc = cc0 + nh * 128 + wn * 32 + n * 16 + (lane & 15);
        bb[nh][n] = (mat == 0) ? bias0[cc] : (mat == 2 ? bias1[cc] : 0.0f);
      }
#pragma unroll
    for (int ph = 0; ph < 2; ++ph){
#pragma unroll
      for (int q2i = 0; q2i < 2; ++q2i){
        const int qd = ph * 2 + q2i;
        const int nh = (qd >> 1) ^ (qd & 1);
#pragma unroll
        for (int m = 0; m < 3; ++m)
#pragma unroll
          for (int n = 0; n < 2; ++n)
#pragma unroll
            for (int j = 0; j < 4; ++j){
              int rr = wm * 48 + m * 16 + (lane >> 4) * 4 + j;   // 0..95
              int c  = nh * 128 + wn * 32 + n * 16 + (lane & 15);// 0..255
              Cs[rr * CSTR + c] = f2bf(acc[qd][m][n][j] + bb[nh][n]);
            }
      }
      __syncthreads();
#pragma unroll
      for (int i = 0; i < 6; ++i){
        int tk  = i * 512 + tid;        // 3072 tasks = 4 panels x 96r x 8sl
        int p   = tk / 768;
        int idx = tk - p * 768;
        int rr  = idx >> 3, sq = idx & 7;
        short8 vv = *reinterpret_cast<const short8*>(&Cs[rr * CSTR + p * 64 + sq * 8]);
        int gr = row0 + ph * 96 + rr;
        int hh = (cc0 >> 6) + p;
        *reinterpret_cast<short8*>(&dst[((size_t)hh * S_TOK + gr) * D_HEAD + sq * 8]) = vv;
      }
      __syncthreads();
    }
  }
#undef MF_Q
}

// ------------- out-proj GEMM: 64x128 tile, BK=32, 480 blocks, high TLP -------------
// 4 waves (2wm x 2wn), wave-tile 32x64 (MR=2, NR=4). LDS 24 KB (2 x 12 KB dbuf)
// -> 4 blocks/CU by LDS; grid 480/256 ~ 2 blocks/CU resident -> 8+ waves/CU so
// per-phase stalls of one block are covered by the other block's MFMA (m114).
// Simple ring-2: vmcnt(0) + barrier per iter, stage t+1 after barrier.
__global__ __launch_bounds__(256, 4) void gemm_out(
    const unsigned short* __restrict__ A,
    const unsigned short* __restrict__ Bp,
    const float* __restrict__ bias0,
    float* __restrict__ Of,
    int K)
{
  constexpr int SLOT = (64 + 128) * 32;           // 6144 shorts per dbuf
  __shared__ __align__(16) unsigned short SH[2 * SLOT];

  const int nwg = gridDim.x;                      // 480 (%8==0)
  const int xcd = blockIdx.x & 7, ix = blockIdx.x >> 3;
  const int wg = xcd * (nwg >> 3) + ix;
  const int bm = wg % 48;                         // row-block fastest: 48 blocks
  const int bn = wg / 48;                         //   share one 327 KB B-panel
  const int row0 = bm * 64, col0 = bn * 128;

  const int tid  = threadIdx.x;
  const int lane = tid & 63;
  const int w    = tid >> 6;
  const int wm   = w >> 1;                        // 0..1
  const int wn   = w & 1;                         // 0..1

  const f32x4 fz = {0.f, 0.f, 0.f, 0.f};
  f32x4 acc[2][4];
#pragma unroll
  for (int m = 0; m < 2; ++m)
#pragma unroll
    for (int n = 0; n < 4; ++n) acc[m][n] = fz;

  // staging: 768 16B-slots (192 rows x 4 slots), 3/thread.
  // swizzle (r5-verified): phys slot p of row r holds k-chunk p ^ ((r>>1)&3)
  auto stage = [&](int buf, int t){
    unsigned short* base = SH + buf * SLOT;
    const int k0 = t << 5;
#pragma unroll
    for (int i = 0; i < 3; ++i){
      int s = i * 256 + tid;
      int r = s >> 2, p = s & 3;
      int ks = p ^ ((r >> 1) & 3);
      const unsigned short* g = (r < 64)
          ? A  + (size_t)(row0 + r) * K + k0 + ks * 8
          : Bp + (size_t)(col0 + (r - 64)) * K + k0 + ks * 8;
      gload_lds16(g, base + s * 8);
    }
  };

  const int nk = K >> 5;                          // 40
  stage(0, 0);
  int buf = 0;
  for (int t = 0; t < nk; ++t){
    asm volatile("s_waitcnt vmcnt(0)" ::: "memory");
    BAR;
    if (t + 1 < nk) stage(buf ^ 1, t + 1);
    const unsigned short* As = SH + buf * SLOT;
    const unsigned short* Bs = As + 64 * 32;
    short8 af[2], bf[4];
#pragma unroll
    for (int m = 0; m < 2; ++m){
      int ra = wm * 32 + m * 16 + (lane & 15);
      int sl = lane >> 4;
      af[m] = *reinterpret_cast<const short8*>(&As[ra * 32 + ((sl ^ ((ra >> 1) & 3))) * 8]);
    }
#pragma unroll
    for (int n = 0; n < 4; ++n){
      int rb = wn * 64 + n * 16 + (lane & 15);
      int sl = lane >> 4;
      bf[n] = *reinterpret_cast<const short8*>(&Bs[rb * 32 + ((sl ^ ((rb >> 1) & 3))) * 8]);
    }
    __builtin_amdgcn_s_setprio(1);
#pragma unroll
    for (int m = 0; m < 2; ++m)
#pragma unroll
      for (int n = 0; n < 4; ++n)
        acc[m][n] = __builtin_amdgcn_mfma_f32_16x16x32_bf16(af[m], bf[n], acc[m][n], 0, 0, 0);
    __builtin_amdgcn_s_setprio(0);
    buf ^= 1;
  }

  float bc[4];
#pragma unroll
  for (int n = 0; n < 4; ++n)
    bc[n] = bias0[col0 + wn * 64 + n * 16 + (lane & 15)];
#pragma unroll
  for (int m = 0; m < 2; ++m)
#pragma unroll
    for (int n = 0; n < 4; ++n){
      int c = col0 + wn * 64 + n * 16 + (lane & 15);
#pragma unroll
      for (int j = 0; j < 4; ++j){
        int r = row0 + wm * 32 + m * 16 + (lane >> 4) * 4 + j;
        Of[(size_t)r * E_DIM + c] = acc[m][n][j] + bc[n];
      }
    }
}

// ---------------- block-diagonal attention (+fused Wo f32->bf16 cvt) ----------------
#define VSTR 200
#define PSTR 72
#define ATTN_BLKS (H_NUM * NSEG * 3)
__global__ __launch_bounds__(256, 3) void attn_kernel(
    const unsigned short* __restrict__ Q,
    const unsigned short* __restrict__ Kb,
    const unsigned short* __restrict__ V,
    const int* __restrict__ cu,
    unsigned short* __restrict__ O,
    const float* __restrict__ Wo,
    unsigned short* __restrict__ wob,
    int nW4)
{
  __shared__ __align__(16) unsigned short Vt[64*VSTR];     // [d][k-row]
  __shared__ __align__(16) unsigned short Pw[4][16][PSTR]; // per-wave scratch

  const int bid  = blockIdx.x;
  if (bid >= ATTN_BLKS){
    int i = (bid - ATTN_BLKS) * 256 + threadIdx.x;
    if (i < nW4){
      float4 v = reinterpret_cast<const float4*>(Wo)[i];
      ushort4 o;
      o.x = f2bf(v.x); o.y = f2bf(v.y); o.z = f2bf(v.z); o.w = f2bf(v.w);
      reinterpret_cast<ushort4*>(wob)[i] = o;
    }
    return;
  }
  const int unit = bid / 3;
  const int third= bid - unit*3;
  const int h    = unit >> 4;
  const int seg  = unit & 15;
  const int s0   = cu[seg];
  const int L    = cu[seg + 1] - s0;
  if (L <= 0) return;

  const int tid  = threadIdx.x;
  const int lane = tid & 63;
  const int w    = tid >> 6;
  const int row0g = third*64 + w*16;

  const unsigned short* qh = Q  + (size_t)h * S_TOK * D_HEAD;
  const unsigned short* kh = Kb + (size_t)h * S_TOK * D_HEAD;
  const unsigned short* vh = V  + (size_t)h * S_TOK * D_HEAD;

#pragma unroll
  for (int i = 0; i < 6; ++i){
    int task = i*256 + tid;            // 1536 tasks = 192 rows x 8 d-groups
    int sr   = task % 192;
    int grp  = task / 192;
    int svr  = s0 + (sr < L ? sr : L - 1);
    short8 vv = *reinterpret_cast<const short8*>(vh + (size_t)svr*64 + grp*8);
#pragma unroll
    for (int j = 0; j < 8; ++j) Vt[(grp*8 + j)*VSTR + sr] = (unsigned short)vv[j];
  }

  short8 qf[2];
#pragma unroll
  for (int kk = 0; kk < 2; ++kk){
    int r  = row0g + (lane & 15);
    int sr = s0 + (r < L ? r : L - 1);
    qf[kk] = *reinterpret_cast<const short8*>(qh + (size_t)sr*64 + kk*32 + (lane >> 4)*8);
  }

  __syncthreads();

  const f32x4 fz = {0.f, 0.f, 0.f, 0.f};
  const float SCL = 0.125f * 1.44269504088896f;

  f32x4 sacc[12];
#pragma unroll
  for (int nt = 0; nt < 12; ++nt) sacc[nt] = fz;

#pragma unroll
  for (int nt = 0; nt < 12; ++nt){
    int rb = nt*16 + (lane & 15);
    int sr = s0 + (rb < L ? rb : L - 1);
    const unsigned short* kr = kh + (size_t)sr*64 + (lane >> 4)*8;
    short8 kf0 = *reinterpret_cast<const short8*>(kr);
    short8 kf1 = *reinterpret_cast<const short8*>(kr + 32);
    sacc[nt] = __builtin_amdgcn_mfma_f32_16x16x32_bf16(qf[0], kf0, sacc[nt], 0, 0, 0);
    sacc[nt] = __builtin_amdgcn_mfma_f32_16x16x32_bf16(qf[1], kf1, sacc[nt], 0, 0, 0);
  }

  float rinv[4];
#pragma unroll
  for (int j = 0; j < 4; ++j){
    float mx = -1e30f;
#pragma unroll
    for (int nt = 0; nt < 12; ++nt){
      int c = nt*16 + (lane & 15);
      float vv = (c < L) ? sacc[nt][j] : -1e30f;
      sacc[nt][j] = vv;
      mx = fmaxf(mx, vv);
    }
    mx = fmaxf(mx, __shfl_xor(mx, 1, 64));
    mx = fmaxf(mx, __shfl_xor(mx, 2, 64));
    mx = fmaxf(mx, __shfl_xor(mx, 4, 64));
    mx = fmaxf(mx, __shfl_xor(mx, 8, 64));
    float sum = 0.f;
#pragma unroll
    for (int nt = 0; nt < 12; ++nt){
      float pp = exp2f((sacc[nt][j] - mx) * SCL);
      sacc[nt][j] = pp;
      sum += pp;
    }
    sum += __shfl_xor(sum, 1, 64);
    sum += __shfl_xor(sum, 2, 64);
    sum += __shfl_xor(sum, 4, 64);
    sum += __shfl_xor(sum, 8, 64);
    rinv[j] = 1.0f / sum;
  }

  f32x4 oacc[4];
#pragma unroll
  for (int nt = 0; nt < 4; ++nt) oacc[nt] = fz;

#pragma unroll
  for (int kk = 0; kk < 6; ++kk){
#pragma unroll
    for (int ntl = 0; ntl < 2; ++ntl){
      int nt = kk*2 + ntl;
#pragma unroll
      for (int j = 0; j < 4; ++j)
        Pw[w][(lane >> 4)*4 + j][ntl*16 + (lane & 15)] = f2bf(sacc[nt][j]);
    }
    short8 pf = *reinterpret_cast<const short8*>(&Pw[w][lane & 15][(lane >> 4)*8]);
#pragma unroll
    for (int nt4 = 0; nt4 < 4; ++nt4){
      int dcol = nt4*16 + (lane & 15);
      short8 vf = *reinterpret_cast<const short8*>(&Vt[dcol*VSTR + kk*32 + (lane >> 4)*8]);
      oacc[nt4] = __builtin_amdgcn_mfma_f32_16x16x32_bf16(pf, vf, oacc[nt4], 0, 0, 0);
    }
  }

#pragma unroll
  for (int nt4 = 0; nt4 < 4; ++nt4)
#pragma unroll
    for (int j = 0; j < 4; ++j)
      Pw[w][(lane >> 4)*4 + j][nt4*16 + (lane & 15)] = f2bf(oacc[nt4][j] * rinv[j]);

  {
    int r = lane >> 2;
    int gr = row0g + r;
    if (gr < L){
#pragma unroll
      for (int part = 0; part < 2; ++part){
        int c0 = (lane & 3)*16 + part*8;
        short8 vv = *reinterpret_cast<const short8*>(&Pw[w][r][c0]);
        *reinterpret_cast<short8*>(&O[(size_t)(s0 + gr) * E_DIM + h*64 + c0]) = vv;
      }
    }
  }
}

// ---------------- host launch ----------------
extern "C" void kernel_launch(void* const* d_in, const int* in_sizes, int n_in,
                              void* d_out, int out_size, void* d_ws, size_t ws_size,
                              hipStream_t stream)
{
  const float* hs = (const float*)d_in[0];
  const float* Wq = (const float*)d_in[1];
  const float* bq = (const float*)d_in[2];
  const float* Wk = (const float*)d_in[3];
  const float* Wv = (const float*)d_in[4];
  const float* bv = (const float*)d_in[5];
  const float* Wo = (const float*)d_in[6];
  const float* bo = (const float*)d_in[7];
  const int*   cu = (const int*)d_in[8];
  float* out = (float*)d_out;

  unsigned short* p = (unsigned short*)d_ws;
  unsigned short* hsb  = p; p += (size_t)S_TOK * E_DIM;
  unsigned short* wqkv = p; p += (size_t)3 * E_DIM * E_DIM;
  unsigned short* wob  = p; p += (size_t)E_DIM * E_DIM;
  unsigned short* qb   = p; p += (size_t)S_TOK * E_DIM;
  unsigned short* kb   = p; p += (size_t)S_TOK * E_DIM;
  unsigned short* vb   = p; p += (size_t)S_TOK * E_DIM;
  unsigned short* aob  = p; p += (size_t)S_TOK * E_DIM;

  const int nHS4 = S_TOK * E_DIM / 4;
  const int nW4  = E_DIM * E_DIM / 4;
  const int nCvt = nHS4 + 3 * nW4;
  cvt_all<<<(nCvt + 255) / 256, 256, 0, stream>>>(hs, Wq, Wk, Wv, hsb, wqkv, nHS4, nW4);

  // QKV: 16 x 15 = 240 blocks of 512 (94% chip fill)
  gemm_qkv<<<(S_TOK/192) * (3*E_DIM/256), 512, 0, stream>>>(
      hsb, wqkv, bq, bv, qb, kb, vb, E_DIM);

  // attention (960 blocks) + fused Wo conversion
  const int cvtWoBlks = (nW4 + 255) / 256;
  attn_kernel<<<ATTN_BLKS + cvtWoBlks, 256, 0, stream>>>(
      qb, kb, vb, cu, aob, Wo, wob, nW4);

  // out-proj: 48 x 10 = 480 blocks of 256, 64x128 tile, high TLP
  gemm_out<<<(S_TOK/64) * (E_DIM/128), 256, 0, stream>>>(
      aob, wob, bo, out, E_DIM);
}

// Round 16
// 83.768 us; speedup vs baseline: 1.0843x; 1.0843x over previous
//
#include <hip/hip_runtime.h>
#include <hip/hip_bf16.h>
#include <stdint.h>

#define S_TOK 3072
#define E_DIM 1280
#define H_NUM 20
#define D_HEAD 64
#define NSEG 16

typedef __attribute__((ext_vector_type(8))) short short8;
typedef __attribute__((ext_vector_type(4))) float f32x4;

__device__ __forceinline__ unsigned short f2bf(float f){
  union { float f; unsigned int i; } u; u.f = f;
  unsigned int r = u.i + 0x7FFFu + ((u.i >> 16) & 1u);
  return (unsigned short)(r >> 16);
}

__device__ __forceinline__ void gload_lds16(const void* g, void* l){
  __builtin_amdgcn_global_load_lds((__attribute__((address_space(1))) void*)(g),
                                   (__attribute__((address_space(3))) void*)(l), 16, 0, 0);
}

// -------- f32 -> bf16 conversions for hs + Wq/Wk/Wv (Wo fused into attn) --------
__global__ void cvt_all(const float* __restrict__ hs,
                        const float* __restrict__ w0, const float* __restrict__ w1,
                        const float* __restrict__ w2,
                        unsigned short* __restrict__ hsb,
                        unsigned short* __restrict__ dqkv,
                        int nHS4, int nW4){
  int i = blockIdx.x * blockDim.x + threadIdx.x;
  const float* src;
  unsigned short* dst;
  size_t sj, dj;
  if (i < nHS4){
    src = hs; dst = hsb; sj = i; dj = i;
  } else {
    int t = i - nHS4;
    int w = t / nW4;
    if (w >= 3) return;
    int j = t - w * nW4;
    src = (w == 0) ? w0 : (w == 1) ? w1 : w2;
    sj = j;
    dst = dqkv; dj = (size_t)w * nW4 + j;
  }
  float4 v = reinterpret_cast<const float4*>(src)[sj];
  ushort4 o;
  o.x = f2bf(v.x); o.y = f2bf(v.y); o.z = f2bf(v.z); o.w = f2bf(v.w);
  reinterpret_cast<ushort4*>(dst)[dj] = o;
}

#define LGKM0 do { asm volatile("s_waitcnt lgkmcnt(0)" ::: "memory");         \
                   __builtin_amdgcn_sched_barrier(0); } while (0)
#define BAR   __builtin_amdgcn_s_barrier()

// ------------- QKV GEMM: 192x256 tile -> 240 blocks (94% chip fill) -------------
// (r14 winner, unchanged) 8 waves (2wm x 4wn), wave-tile 96x64, BK=64, dbuf,
// per-phase counted vmcnt with explicit ledger; stages target opposite dbuf.
__global__ __launch_bounds__(512, 2) void gemm_qkv(
    const unsigned short* __restrict__ A,
    const unsigned short* __restrict__ Bp,
    const float* __restrict__ bias0,   // bq
    const float* __restrict__ bias1,   // bv
    unsigned short* __restrict__ Oq,
    unsigned short* __restrict__ Ok,
    unsigned short* __restrict__ Ov,
    int K)
{
  constexpr int SLOT = (192 + 256) * 64;          // 28672 shorts per dbuf
  __shared__ __align__(16) unsigned short SH[2 * SLOT];

  const int nwg = gridDim.x;
  const int xcd = blockIdx.x & 7, ix = blockIdx.x >> 3;
  const int wg = xcd * (nwg >> 3) + ix;
  const int st = wg / 20, ii = wg % 20;           // st: 0..11
  const int bm = (st / 3) * 4 + ii / 5;           // 0..15
  const int bn = (st % 3) * 5 + ii % 5;           // 0..14
  const int row0 = bm * 192, col0 = bn * 256;

  const int tid  = threadIdx.x;
  const int lane = tid & 63;
  const int w    = tid >> 6;
  const int wm   = w >> 2;                        // 0..1
  const int wn   = w & 3;                         // 0..3

  const f32x4 fz = {0.f, 0.f, 0.f, 0.f};
  f32x4 acc[4][3][2];
#pragma unroll
  for (int qd = 0; qd < 4; ++qd)
#pragma unroll
    for (int m = 0; m < 3; ++m)
#pragma unroll
      for (int n = 0; n < 2; ++n) acc[qd][m][n] = fz;

  auto stA = [&](int t){                          // full A: 192x64, 3 loads
    unsigned short* d = SH + (t & 1) * SLOT;
    const unsigned short* g = A + (size_t)row0 * K + (t << 6);
#pragma unroll
    for (int i = 0; i < 3; ++i){
      int s = i * 512 + tid;
      int r = s >> 3, ks = (s & 7) ^ (r & 7);
      gload_lds16(g + (size_t)r * K + ks * 8, d + s * 8);
    }
  };
  auto stB = [&](int h, int t){                   // B half: 128x64, 2 loads
    unsigned short* d = SH + (t & 1) * SLOT + 12288 + h * 8192;
    const unsigned short* g = Bp + (size_t)(col0 + h * 128) * K + (t << 6);
#pragma unroll
    for (int i = 0; i < 2; ++i){
      int s = i * 512 + tid;
      int r = s >> 3, ks = (s & 7) ^ (r & 7);
      gload_lds16(g + (size_t)r * K + ks * 8, d + s * 8);
    }
  };

  short8 af[3][2], bf0[2][2], bf1[2][2];
  auto RA = [&](int mh, int db){
    const unsigned short* Ah = SH + db * SLOT;
#pragma unroll
    for (int m = 0; m < 3; ++m){
      int ra = mh * 96 + wm * 48 + m * 16 + (lane & 15);
#pragma unroll
      for (int kk = 0; kk < 2; ++kk){
        int sl = kk * 4 + (lane >> 4);
        af[m][kk] = *reinterpret_cast<const short8*>(&Ah[ra * 64 + ((sl ^ (ra & 7))) * 8]);
      }
    }
  };
  auto RB = [&](int nh, int db, short8 (*bf)[2]){
    const unsigned short* Bb = SH + db * SLOT + 12288;
#pragma unroll
    for (int n = 0; n < 2; ++n){
      int rb = nh * 128 + wn * 32 + n * 16 + (lane & 15);
#pragma unroll
      for (int kk = 0; kk < 2; ++kk){
        int sl = kk * 4 + (lane >> 4);
        bf[n][kk] = *reinterpret_cast<const short8*>(&Bb[rb * 64 + ((sl ^ (rb & 7))) * 8]);
      }
    }
  };

#define MF_Q(QD, BF)                                                          \
  do {                                                                        \
    __builtin_amdgcn_s_setprio(1);                                            \
    _Pragma("unroll")                                                         \
    for (int kk = 0; kk < 2; ++kk)                                            \
      _Pragma("unroll")                                                       \
      for (int m = 0; m < 3; ++m)                                             \
        _Pragma("unroll")                                                     \
        for (int n = 0; n < 2; ++n)                                           \
          acc[QD][m][n] = __builtin_amdgcn_mfma_f32_16x16x32_bf16(            \
              af[m][kk], BF[n][kk], acc[QD][m][n], 0, 0, 0);                  \
    __builtin_amdgcn_s_setprio(0);                                            \
  } while (0)

  const int nk = K >> 6;                          // 20
  stA(0); stB(0, 0); stB(1, 0);                   // 7 loads out
  for (int t = 0; t < nk; ++t){
    const int db = t & 1;
    const bool nx = (t + 1 < nk);
    // q0 (0,0): entry out=7 {A,B0,B1 of t}; force A+B0 -> leave 2
    asm volatile("s_waitcnt vmcnt(2)" ::: "memory");
    BAR;
    RA(0, db); RB(0, db, bf0);
    if (nx) stA(t + 1);                           // out: 2 -> 5
    LGKM0; MF_Q(0, bf0);
    // q1 (0,1): force B1(t) -> leave A(t+1)=3
    if (nx) asm volatile("s_waitcnt vmcnt(3)" ::: "memory");
    else    asm volatile("s_waitcnt vmcnt(0)" ::: "memory");
    BAR;
    RB(1, db, bf1);
    if (nx) stB(0, t + 1);                        // out: 3 -> 5
    LGKM0; MF_Q(1, bf1);
    // q2 (1,1): A(t) already forced at q0 - no wait
    BAR;
    RA(1, db);
    if (nx) stB(1, t + 1);                        // out: 5 -> 7
    LGKM0; MF_Q(2, bf1);
    // q3 (1,0): register-only
    BAR;
    MF_Q(3, bf0);
  }
  __syncthreads();

  // ---- coalesced scatter epilogue: two 96-row phases staged in LDS ----
  {
    unsigned short* Cs = SH;
    const int CSTR = 264;                         // 96 x 264 = 25344 <= SLOT
    const int mat = col0 / E_DIM;                 // 1280 % 256 == 0
    const int cc0 = col0 - mat * E_DIM;
    unsigned short* dst = (mat == 0) ? Oq : ((mat == 1) ? Ok : Ov);
    float bb[2][2];
#pragma unroll
    for (int nh = 0; nh < 2; ++nh)
#pragma unroll
      for (int n = 0; n < 2; ++n){
        int cc = cc0 + nh * 128 + wn * 32 + n * 16 + (lane & 15);
        bb[nh][n] = (mat == 0) ? bias0[cc] : (mat == 2 ? bias1[cc] : 0.0f);
      }
#pragma unroll
    for (int ph = 0; ph < 2; ++ph){
#pragma unroll
      for (int q2i = 0; q2i < 2; ++q2i){
        const int qd = ph * 2 + q2i;
        const int nh = (qd >> 1) ^ (qd & 1);
#pragma unroll
        for (int m = 0; m < 3; ++m)
#pragma unroll
          for (int n = 0; n < 2; ++n)
#pragma unroll
            for (int j = 0; j < 4; ++j){
              int rr = wm * 48 + m * 16 + (lane >> 4) * 4 + j;   // 0..95
              int c  = nh * 128 + wn * 32 + n * 16 + (lane & 15);// 0..255
              Cs[rr * CSTR + c] = f2bf(acc[qd][m][n][j] + bb[nh][n]);
            }
      }
      __syncthreads();
#pragma unroll
      for (int i = 0; i < 6; ++i){
        int tk  = i * 512 + tid;        // 3072 tasks = 4 panels x 96r x 8sl
        int p   = tk / 768;
        int idx = tk - p * 768;
        int rr  = idx >> 3, sq = idx & 7;
        short8 vv = *reinterpret_cast<const short8*>(&Cs[rr * CSTR + p * 64 + sq * 8]);
        int gr = row0 + ph * 96 + rr;
        int hh = (cc0 >> 6) + p;
        *reinterpret_cast<short8*>(&dst[((size_t)hh * S_TOK + gr) * D_HEAD + sq * 8]) = vv;
      }
      __syncthreads();
    }
  }
#undef MF_Q
}

// ------------- out-proj GEMM: 128x128, 512 threads, ring-3 counted-vmcnt -------------
// 8 waves (2wm x 4wn), wave-tile 64x32 (MR=4, NR=2), BK=64. Ring-3 slots
// (96 KB): iter t issues stage(t+1 -> slot (t+1)%3) THEN vmcnt(4) (outstanding
// = t's 4 + t+1's 4 -> forces exactly tile t; 1 full iter of latency cover;
// never drains below 4 mid-loop). Write-after-read: slot (t+1)%3 was read at
// iter t-2, drained (lgkm before its MFMAs) before BAR(t-1); stage@t follows
// BAR(t-1). 2 waves/SIMD = 2x the latency-hiding of the old 256-thread kernel.
__global__ __launch_bounds__(512, 2) void gemm_out(
    const unsigned short* __restrict__ A,
    const unsigned short* __restrict__ Bp,
    const float* __restrict__ bias0,
    float* __restrict__ Of,
    int K)
{
  constexpr int SLOT = 256 * 64;                  // 16384 shorts per slot
  __shared__ __align__(16) unsigned short SH[3 * SLOT];   // 96 KB

  const int nwg = gridDim.x;                      // 240 (%8==0)
  const int xcd = blockIdx.x & 7, ix = blockIdx.x >> 3;
  const int wg = xcd * (nwg >> 3) + ix;
  const int st = wg / 20, ii = wg % 20;           // st 0..11
  const int bm = (st / 2) * 4 + ii / 5;           // 0..23
  const int bn = (st % 2) * 5 + ii % 5;           // 0..9
  const int row0 = bm * 128, col0 = bn * 128;

  const int tid  = threadIdx.x;
  const int lane = tid & 63;
  const int w    = tid >> 6;
  const int wm   = w >> 2;                        // 0..1
  const int wn   = w & 3;                         // 0..3

  const f32x4 fz = {0.f, 0.f, 0.f, 0.f};
  f32x4 acc[4][2];
#pragma unroll
  for (int m = 0; m < 4; ++m)
#pragma unroll
    for (int n = 0; n < 2; ++n) acc[m][n] = fz;

  // stage one K-tile: 2048 16B-slots (A 128x64 + B 128x64), 4 loads/thread
  auto stage = [&](int sl, int t){
    unsigned short* base = SH + sl * SLOT;
    const int k0 = t << 6;
#pragma unroll
    for (int i = 0; i < 4; ++i){
      int s = i * 512 + tid;
      int r = s >> 3, ks = (s & 7) ^ (r & 7);
      const unsigned short* g = (r < 128)
          ? A  + (size_t)(row0 + r) * K + k0 + ks * 8
          : Bp + (size_t)(col0 + (r - 128)) * K + k0 + ks * 8;
      gload_lds16(g, base + s * 8);
    }
  };

  const int nk = K >> 6;                          // 20
  stage(0, 0);
  for (int t = 0; t < nk; ++t){
    if (t + 1 < nk){
      stage((t + 1) % 3, t + 1);
      asm volatile("s_waitcnt vmcnt(4)" ::: "memory");   // tile t fully landed
    } else {
      asm volatile("s_waitcnt vmcnt(0)" ::: "memory");
    }
    BAR;
    const unsigned short* As = SH + (t % 3) * SLOT;
    const unsigned short* Bs = As + 128 * 64;
    short8 af[4][2], bf[2][2];
#pragma unroll
    for (int m = 0; m < 4; ++m){
      int ra = wm * 64 + m * 16 + (lane & 15);
#pragma unroll
      for (int kk = 0; kk < 2; ++kk){
        int sl = kk * 4 + (lane >> 4);
        af[m][kk] = *reinterpret_cast<const short8*>(&As[ra * 64 + ((sl ^ (ra & 7))) * 8]);
      }
    }
#pragma unroll
    for (int n = 0; n < 2; ++n){
      int rb = wn * 32 + n * 16 + (lane & 15);
#pragma unroll
      for (int kk = 0; kk < 2; ++kk){
        int sl = kk * 4 + (lane >> 4);
        bf[n][kk] = *reinterpret_cast<const short8*>(&Bs[rb * 64 + ((sl ^ (rb & 7))) * 8]);
      }
    }
    __builtin_amdgcn_s_setprio(1);
#pragma unroll
    for (int kk = 0; kk < 2; ++kk)
#pragma unroll
      for (int m = 0; m < 4; ++m)
#pragma unroll
        for (int n = 0; n < 2; ++n)
          acc[m][n] = __builtin_amdgcn_mfma_f32_16x16x32_bf16(af[m][kk], bf[n][kk], acc[m][n], 0, 0, 0);
    __builtin_amdgcn_s_setprio(0);
  }

  float bc[2];
#pragma unroll
  for (int n = 0; n < 2; ++n)
    bc[n] = bias0[col0 + wn * 32 + n * 16 + (lane & 15)];
#pragma unroll
  for (int m = 0; m < 4; ++m)
#pragma unroll
    for (int n = 0; n < 2; ++n){
      int c = col0 + wn * 32 + n * 16 + (lane & 15);
#pragma unroll
      for (int j = 0; j < 4; ++j){
        int r = row0 + wm * 64 + m * 16 + (lane >> 4) * 4 + j;
        Of[(size_t)r * E_DIM + c] = acc[m][n][j] + bc[n];
      }
    }
}

// ---------------- block-diagonal attention (+fused Wo f32->bf16 cvt) ----------------
#define VSTR 200
#define PSTR 72
#define ATTN_BLKS (H_NUM * NSEG * 3)
__global__ __launch_bounds__(256, 3) void attn_kernel(
    const unsigned short* __restrict__ Q,
    const unsigned short* __restrict__ Kb,
    const unsigned short* __restrict__ V,
    const int* __restrict__ cu,
    unsigned short* __restrict__ O,
    const float* __restrict__ Wo,
    unsigned short* __restrict__ wob,
    int nW4)
{
  __shared__ __align__(16) unsigned short Vt[64*VSTR];     // [d][k-row]
  __shared__ __align__(16) unsigned short Pw[4][16][PSTR]; // per-wave scratch

  const int bid  = blockIdx.x;
  if (bid >= ATTN_BLKS){
    int i = (bid - ATTN_BLKS) * 256 + threadIdx.x;
    if (i < nW4){
      float4 v = reinterpret_cast<const float4*>(Wo)[i];
      ushort4 o;
      o.x = f2bf(v.x); o.y = f2bf(v.y); o.z = f2bf(v.z); o.w = f2bf(v.w);
      reinterpret_cast<ushort4*>(wob)[i] = o;
    }
    return;
  }
  const int unit = bid / 3;
  const int third= bid - unit*3;
  const int h    = unit >> 4;
  const int seg  = unit & 15;
  const int s0   = cu[seg];
  const int L    = cu[seg + 1] - s0;
  if (L <= 0) return;

  const int tid  = threadIdx.x;
  const int lane = tid & 63;
  const int w    = tid >> 6;
  const int row0g = third*64 + w*16;

  const unsigned short* qh = Q  + (size_t)h * S_TOK * D_HEAD;
  const unsigned short* kh = Kb + (size_t)h * S_TOK * D_HEAD;
  const unsigned short* vh = V  + (size_t)h * S_TOK * D_HEAD;

#pragma unroll
  for (int i = 0; i < 6; ++i){
    int task = i*256 + tid;            // 1536 tasks = 192 rows x 8 d-groups
    int sr   = task % 192;
    int grp  = task / 192;
    int svr  = s0 + (sr < L ? sr : L - 1);
    short8 vv = *reinterpret_cast<const short8*>(vh + (size_t)svr*64 + grp*8);
#pragma unroll
    for (int j = 0; j < 8; ++j) Vt[(grp*8 + j)*VSTR + sr] = (unsigned short)vv[j];
  }

  short8 qf[2];
#pragma unroll
  for (int kk = 0; kk < 2; ++kk){
    int r  = row0g + (lane & 15);
    int sr = s0 + (r < L ? r : L - 1);
    qf[kk] = *reinterpret_cast<const short8*>(qh + (size_t)sr*64 + kk*32 + (lane >> 4)*8);
  }

  __syncthreads();

  const f32x4 fz = {0.f, 0.f, 0.f, 0.f};
  const float SCL = 0.125f * 1.44269504088896f;

  f32x4 sacc[12];
#pragma unroll
  for (int nt = 0; nt < 12; ++nt) sacc[nt] = fz;

#pragma unroll
  for (int nt = 0; nt < 12; ++nt){
    int rb = nt*16 + (lane & 15);
    int sr = s0 + (rb < L ? rb : L - 1);
    const unsigned short* kr = kh + (size_t)sr*64 + (lane >> 4)*8;
    short8 kf0 = *reinterpret_cast<const short8*>(kr);
    short8 kf1 = *reinterpret_cast<const short8*>(kr + 32);
    sacc[nt] = __builtin_amdgcn_mfma_f32_16x16x32_bf16(qf[0], kf0, sacc[nt], 0, 0, 0);
    sacc[nt] = __builtin_amdgcn_mfma_f32_16x16x32_bf16(qf[1], kf1, sacc[nt], 0, 0, 0);
  }

  float rinv[4];
#pragma unroll
  for (int j = 0; j < 4; ++j){
    float mx = -1e30f;
#pragma unroll
    for (int nt = 0; nt < 12; ++nt){
      int c = nt*16 + (lane & 15);
      float vv = (c < L) ? sacc[nt][j] : -1e30f;
      sacc[nt][j] = vv;
      mx = fmaxf(mx, vv);
    }
    mx = fmaxf(mx, __shfl_xor(mx, 1, 64));
    mx = fmaxf(mx, __shfl_xor(mx, 2, 64));
    mx = fmaxf(mx, __shfl_xor(mx, 4, 64));
    mx = fmaxf(mx, __shfl_xor(mx, 8, 64));
    float sum = 0.f;
#pragma unroll
    for (int nt = 0; nt < 12; ++nt){
      float pp = exp2f((sacc[nt][j] - mx) * SCL);
      sacc[nt][j] = pp;
      sum += pp;
    }
    sum += __shfl_xor(sum, 1, 64);
    sum += __shfl_xor(sum, 2, 64);
    sum += __shfl_xor(sum, 4, 64);
    sum += __shfl_xor(sum, 8, 64);
    rinv[j] = 1.0f / sum;
  }

  f32x4 oacc[4];
#pragma unroll
  for (int nt = 0; nt < 4; ++nt) oacc[nt] = fz;

#pragma unroll
  for (int kk = 0; kk < 6; ++kk){
#pragma unroll
    for (int ntl = 0; ntl < 2; ++ntl){
      int nt = kk*2 + ntl;
#pragma unroll
      for (int j = 0; j < 4; ++j)
        Pw[w][(lane >> 4)*4 + j][ntl*16 + (lane & 15)] = f2bf(sacc[nt][j]);
    }
    short8 pf = *reinterpret_cast<const short8*>(&Pw[w][lane & 15][(lane >> 4)*8]);
#pragma unroll
    for (int nt4 = 0; nt4 < 4; ++nt4){
      int dcol = nt4*16 + (lane & 15);
      short8 vf = *reinterpret_cast<const short8*>(&Vt[dcol*VSTR + kk*32 + (lane >> 4)*8]);
      oacc[nt4] = __builtin_amdgcn_mfma_f32_16x16x32_bf16(pf, vf, oacc[nt4], 0, 0, 0);
    }
  }

#pragma unroll
  for (int nt4 = 0; nt4 < 4; ++nt4)
#pragma unroll
    for (int j = 0; j < 4; ++j)
      Pw[w][(lane >> 4)*4 + j][nt4*16 + (lane & 15)] = f2bf(oacc[nt4][j] * rinv[j]);

  {
    int r = lane >> 2;
    int gr = row0g + r;
    if (gr < L){
#pragma unroll
      for (int part = 0; part < 2; ++part){
        int c0 = (lane & 3)*16 + part*8;
        short8 vv = *reinterpret_cast<const short8*>(&Pw[w][r][c0]);
        *reinterpret_cast<short8*>(&O[(size_t)(s0 + gr) * E_DIM + h*64 + c0]) = vv;
      }
    }
  }
}

// ---------------- host launch ----------------
extern "C" void kernel_launch(void* const* d_in, const int* in_sizes, int n_in,
                              void* d_out, int out_size, void* d_ws, size_t ws_size,
                              hipStream_t stream)
{
  const float* hs = (const float*)d_in[0];
  const float* Wq = (const float*)d_in[1];
  const float* bq = (const float*)d_in[2];
  const float* Wk = (const float*)d_in[3];
  const float* Wv = (const float*)d_in[4];
  const float* bv = (const float*)d_in[5];
  const float* Wo = (const float*)d_in[6];
  const float* bo = (const float*)d_in[7];
  const int*   cu = (const int*)d_in[8];
  float* out = (float*)d_out;

  unsigned short* p = (unsigned short*)d_ws;
  unsigned short* hsb  = p; p += (size_t)S_TOK * E_DIM;
  unsigned short* wqkv = p; p += (size_t)3 * E_DIM * E_DIM;
  unsigned short* wob  = p; p += (size_t)E_DIM * E_DIM;
  unsigned short* qb   = p; p += (size_t)S_TOK * E_DIM;
  unsigned short* kb   = p; p += (size_t)S_TOK * E_DIM;
  unsigned short* vb   = p; p += (size_t)S_TOK * E_DIM;
  unsigned short* aob  = p; p += (size_t)S_TOK * E_DIM;

  const int nHS4 = S_TOK * E_DIM / 4;
  const int nW4  = E_DIM * E_DIM / 4;
  const int nCvt = nHS4 + 3 * nW4;
  cvt_all<<<(nCvt + 255) / 256, 256, 0, stream>>>(hs, Wq, Wk, Wv, hsb, wqkv, nHS4, nW4);

  // QKV: 16 x 15 = 240 blocks of 512 (94% chip fill)
  gemm_qkv<<<(S_TOK/192) * (3*E_DIM/256), 512, 0, stream>>>(
      hsb, wqkv, bq, bv, qb, kb, vb, E_DIM);

  // attention (960 blocks) + fused Wo conversion
  const int cvtWoBlks = (nW4 + 255) / 256;
  attn_kernel<<<ATTN_BLKS + cvtWoBlks, 256, 0, stream>>>(
      qb, kb, vb, cu, aob, Wo, wob, nW4);

  // out-proj: 24 x 10 = 240 blocks of 512, 128x128 tile, ring-3 counted vmcnt
  gemm_out<<<(S_TOK/128) * (E_DIM/128), 512, 0, stream>>>(
      aob, wob, bo, out, E_DIM);
}